// Round 6
// baseline (1030.634 us; speedup 1.0000x reference)
//
#include <hip/hip_runtime.h>

namespace {

typedef float v2f __attribute__((ext_vector_type(2)));

constexpr int T_SEQ = 2048;
constexpr int B_SZ  = 512;
constexpr int C_IN  = 8;
constexpr int H_SZ  = 20;
constexpr int P_LEN = 16;                 // steps per phase (barrier period)
constexpr int N_PH  = T_SEQ / P_LEN;      // 128 phases
constexpr int RING  = 2 * P_LEN;          // 32-slot h0 handoff ring
constexpr int QB    = 4;                  // batches (wave-pairs) per block
constexpr float LOG2E = 1.44269504088896340736f;

__device__ __forceinline__ float rlane(float v, int lane) {
  return __int_as_float(__builtin_amdgcn_readlane(__float_as_int(v), lane));
}

template<int S>
__device__ __forceinline__ float quad_bcast(float v) {
  return __int_as_float(__builtin_amdgcn_update_dpp(
      __float_as_int(v), __float_as_int(v), S * 0x55, 0xF, 0xF, true));
}

__device__ __forceinline__ v2f fma2(v2f a, v2f b, v2f c) {
  return __builtin_elementwise_fma(a, b, c);   // -> v_pk_fma_f32
}
__device__ __forceinline__ v2f splat2(float s) { v2f r; r.x = s; r.y = s; return r; }
__device__ __forceinline__ v2f zero2() { v2f r; r.x = 0.f; r.y = 0.f; return r; }

// Elementwise activation on both gate sets: sigmoid (g!=2) / tanh (g==2).
// cm has log2e pre-folded; tanh(x) = 2*sigmoid(2x)-1.
__device__ __forceinline__ v2f act2(v2f a, float cm, float am, float ad) {
  float ex = __builtin_amdgcn_exp2f(a.x * cm);
  float ey = __builtin_amdgcn_exp2f(a.y * cm);
  float sx = __builtin_amdgcn_rcpf(1.0f + ex);
  float sy = __builtin_amdgcn_rcpf(1.0f + ey);
  v2f r; r.x = __fmaf_rn(sx, am, ad); r.y = __fmaf_rn(sy, am, ad);
  return r;
}

__device__ __forceinline__ float fast_tanh(float a) {
  float e = __builtin_amdgcn_exp2f(a * (-2.0f * LOG2E));
  float s = __builtin_amdgcn_rcpf(1.0f + e);
  return __fmaf_rn(s, 2.0f, -1.0f);
}

// h[k] broadcast from lane-distributed regs (set1 at lanes 4k, k<16;
// set2 value for k=16..19 at lanes 4*(k-16)).
#define H_BCAST(ha, hb, k) (((k) < 16) ? rlane((ha), 4 * (k)) : rlane((hb), 4 * ((k) - 16)))

// 8 waves/block => 2 resident waves per SIMD (forced by block shape).
// Per-wave code is the round-0 baseline verbatim; only geometry changed.
__global__ __attribute__((amdgpu_flat_work_group_size(512, 512),
                          amdgpu_waves_per_eu(2, 2)))
void lstm2_pair(const float* __restrict__ x,
                const float* __restrict__ Wih0, const float* __restrict__ Whh0,
                const float* __restrict__ bih0, const float* __restrict__ bhh0,
                const float* __restrict__ Wih1, const float* __restrict__ Whh1,
                const float* __restrict__ bih1, const float* __restrict__ bhh1,
                float* __restrict__ out)
{
  // Per-batch h0 handoff ring + x staging (4 batches per block).
  __shared__ __align__(16) float hbuf[QB][RING][H_SZ];
  __shared__ __align__(16) float xbuf[QB][2][P_LEN * C_IN];

  const int tid  = threadIdx.x;
  const int wv   = tid >> 6;
  const int q    = wv >> 1;          // batch-pair index within block (0..3)
  const int role = wv & 1;           // 0 = layer-0 wave, 1 = layer-1 wave
  const int l    = tid & 63;
  const int b    = blockIdx.x * QB + q;
  const int k1   = l >> 2;           // 0..15
  const int g    = l & 3;            // gate slot: 0=i 1=f 2=g 3=o
  const int k2   = 16 + (k1 & 3);    // 16..19 (replicated)
  const int j1   = g * H_SZ + k1;
  const int j2   = g * H_SZ + k2;

  const bool  isg = (g == 2);
  const float cm  = isg ? (-2.0f * LOG2E) : (-LOG2E);
  const float am  = isg ?  2.0f : 1.0f;
  const float ad  = isg ? -1.0f : 0.0f;

  if (role == 0) {
    // ================= layer-0 producer wave =================
    v2f wx1[C_IN / 2], wx2[C_IN / 2];  // Wih0 rows j1/j2, k-packed
    v2f wh[H_SZ];                      // {Whh0[j1][k], Whh0[j2][k]} gate-set packed
#pragma unroll
    for (int t = 0; t < C_IN / 2; ++t) {
      wx1[t].x = Wih0[j1 * C_IN + 2 * t]; wx1[t].y = Wih0[j1 * C_IN + 2 * t + 1];
      wx2[t].x = Wih0[j2 * C_IN + 2 * t]; wx2[t].y = Wih0[j2 * C_IN + 2 * t + 1];
    }
#pragma unroll
    for (int k = 0; k < H_SZ; ++k) {
      wh[k].x = Whh0[j1 * H_SZ + k]; wh[k].y = Whh0[j2 * H_SZ + k];
    }
    v2f bias2; bias2.x = bih0[j1] + bhh0[j1]; bias2.y = bih0[j2] + bhh0[j2];

    float ha = 0.f, ca = 0.f, hb = 0.f, cb = 0.f;

    // Per-lane x slice: element e in [0,128) of a phase -> step e>>3, channel e&7.
    const float* xl = x + (size_t)(l >> 3) * (B_SZ * C_IN) + b * C_IN + (l & 7);
    const size_t halfph = (size_t)8 * B_SZ * C_IN;
    const size_t phstr  = (size_t)P_LEN * B_SZ * C_IN;

    // Bootstrap: phase 0 committed now; phase 1 stays in flight a whole phase.
    {
      float v0 = xl[0], v1 = xl[halfph];
      xbuf[q][0][l] = v0; xbuf[q][0][64 + l] = v1;
    }
    float n0 = xl[phstr], n1 = xl[phstr + halfph];

    for (int p = 0; p <= N_PH; ++p) {
      if (p < N_PH) {
        const int buf = p & 1;
        float4 xc0 = ((const float4*)&xbuf[q][buf][0])[0];
        float4 xc1 = ((const float4*)&xbuf[q][buf][0])[1];
        for (int j = 0; j < P_LEN; ++j) {
          const int n = p * P_LEN + j;
          v2f xp[4];
          xp[0].x = xc0.x; xp[0].y = xc0.y; xp[1].x = xc0.z; xp[1].y = xc0.w;
          xp[2].x = xc1.x; xp[2].y = xc1.y; xp[3].x = xc1.z; xp[3].y = xc1.w;
          if (j + 1 < P_LEN) {           // one-step-ahead x prefetch (LDS bcast)
            xc0 = ((const float4*)&xbuf[q][buf][(j + 1) * C_IN])[0];
            xc1 = ((const float4*)&xbuf[q][buf][(j + 1) * C_IN])[1];
          }

          // Recurrent dot, gate-set packed, 2 accs (chain depth 10).
          v2f A0 = bias2, A1 = zero2();
#pragma unroll
          for (int k = 0; k < H_SZ; k += 2) {
            float h0 = H_BCAST(ha, hb, k);
            float h1 = H_BCAST(ha, hb, k + 1);
            A0 = fma2(wh[k],     splat2(h0), A0);
            A1 = fma2(wh[k + 1], splat2(h1), A1);
          }
          // Input dot, k-packed per gate set.
          v2f X1 = zero2(), X2 = zero2();
#pragma unroll
          for (int t = 0; t < C_IN / 2; ++t) {
            X1 = fma2(wx1[t], xp[t], X1);
            X2 = fma2(wx2[t], xp[t], X2);
          }
          v2f A = A0 + A1;
          A.x += X1.x + X1.y;
          A.y += X2.x + X2.y;

          v2f act = act2(A, cm, am, ad);
          float iv = quad_bcast<0>(act.x), fv = quad_bcast<1>(act.x);
          float gv = quad_bcast<2>(act.x), ov = quad_bcast<3>(act.x);
          ca = __fmaf_rn(fv, ca, iv * gv);
          ha = ov * fast_tanh(ca);
          iv = quad_bcast<0>(act.y); fv = quad_bcast<1>(act.y);
          gv = quad_bcast<2>(act.y); ov = quad_bcast<3>(act.y);
          cb = __fmaf_rn(fv, cb, iv * gv);
          hb = ov * fast_tanh(cb);

          const int slot = n & (RING - 1);
          if (g == 0) {
            hbuf[q][slot][k1] = ha;
            if (k1 < 4) hbuf[q][slot][16 + k1] = hb;
          }
        }
        // Commit next phase's x (in flight ~16 steps); issue load for p+2.
        if (p + 1 < N_PH) { xbuf[q][(p + 1) & 1][l] = n0; xbuf[q][(p + 1) & 1][64 + l] = n1; }
        if (p + 2 < N_PH) {
          n0 = xl[(size_t)(p + 2) * phstr];
          n1 = xl[(size_t)(p + 2) * phstr + halfph];
        }
      }
      __syncthreads();   // 129 barriers total, all 8 waves
    }
  } else {
    // ================= layer-1 consumer wave (lags one phase) =================
    v2f wy1[H_SZ / 2], wy2[H_SZ / 2];  // Wih1 rows j1/j2, k-packed
    v2f wq[H_SZ];                      // {Whh1[j1][k], Whh1[j2][k]} gate-set packed
#pragma unroll
    for (int t = 0; t < H_SZ / 2; ++t) {
      wy1[t].x = Wih1[j1 * H_SZ + 2 * t]; wy1[t].y = Wih1[j1 * H_SZ + 2 * t + 1];
      wy2[t].x = Wih1[j2 * H_SZ + 2 * t]; wy2[t].y = Wih1[j2 * H_SZ + 2 * t + 1];
    }
#pragma unroll
    for (int k = 0; k < H_SZ; ++k) {
      wq[k].x = Whh1[j1 * H_SZ + k]; wq[k].y = Whh1[j2 * H_SZ + k];
    }
    v2f bias2; bias2.x = bih1[j1] + bhh1[j1]; bias2.y = bih1[j2] + bhh1[j2];

    float ha = 0.f, ca = 0.f, hb = 0.f, cb = 0.f;
    float* op = out + b * H_SZ;

    auto stepW1 = [&](int n, const float4 (&yq)[5]) {
      v2f yp[H_SZ / 2];
      yp[0].x = yq[0].x; yp[0].y = yq[0].y; yp[1].x = yq[0].z; yp[1].y = yq[0].w;
      yp[2].x = yq[1].x; yp[2].y = yq[1].y; yp[3].x = yq[1].z; yp[3].y = yq[1].w;
      yp[4].x = yq[2].x; yp[4].y = yq[2].y; yp[5].x = yq[2].z; yp[5].y = yq[2].w;
      yp[6].x = yq[3].x; yp[6].y = yq[3].y; yp[7].x = yq[3].z; yp[7].y = yq[3].w;
      yp[8].x = yq[4].x; yp[8].y = yq[4].y; yp[9].x = yq[4].z; yp[9].y = yq[4].w;

      // y-stream: k-packed per gate set, 2 accs each (chain depth 5).
      v2f Y1a = zero2(), Y1b = zero2(), Y2a = zero2(), Y2b = zero2();
#pragma unroll
      for (int t = 0; t < H_SZ / 2; t += 2) {
        Y1a = fma2(wy1[t],     yp[t],     Y1a);
        Y2a = fma2(wy2[t],     yp[t],     Y2a);
        Y1b = fma2(wy1[t + 1], yp[t + 1], Y1b);
        Y2b = fma2(wy2[t + 1], yp[t + 1], Y2b);
      }
      // q-stream (h1 recurrence): gate-set packed, 2 accs (chain depth 10).
      v2f Q0 = bias2, Q1 = zero2();
#pragma unroll
      for (int k = 0; k < H_SZ; k += 2) {
        float q0 = H_BCAST(ha, hb, k);
        float q1 = H_BCAST(ha, hb, k + 1);
        Q0 = fma2(wq[k],     splat2(q0), Q0);
        Q1 = fma2(wq[k + 1], splat2(q1), Q1);
      }
      v2f A = Q0 + Q1;
      v2f Y1 = Y1a + Y1b, Y2 = Y2a + Y2b;
      A.x += Y1.x + Y1.y;
      A.y += Y2.x + Y2.y;

      v2f act = act2(A, cm, am, ad);
      float iv = quad_bcast<0>(act.x), fv = quad_bcast<1>(act.x);
      float gv = quad_bcast<2>(act.x), ov = quad_bcast<3>(act.x);
      ca = __fmaf_rn(fv, ca, iv * gv);
      ha = ov * fast_tanh(ca);
      iv = quad_bcast<0>(act.y); fv = quad_bcast<1>(act.y);
      gv = quad_bcast<2>(act.y); ov = quad_bcast<3>(act.y);
      cb = __fmaf_rn(fv, cb, iv * gv);
      hb = ov * fast_tanh(cb);

      if (g == 0) {
        op[k1] = ha;
        if (k1 < 4) op[16 + k1] = hb;
      }
      op += B_SZ * H_SZ;
    };

    for (int p = 0; p <= N_PH; ++p) {
      if (p >= 1) {
        const int base = (p - 1) * P_LEN;
        float4 yA[5], yB[5];
        {
          const float4* s = (const float4*)hbuf[q][base & (RING - 1)];
          yA[0] = s[0]; yA[1] = s[1]; yA[2] = s[2]; yA[3] = s[3]; yA[4] = s[4];
        }
        {
          const float4* s = (const float4*)hbuf[q][(base + 1) & (RING - 1)];
          yB[0] = s[0]; yB[1] = s[1]; yB[2] = s[2]; yB[3] = s[3]; yB[4] = s[4];
        }
        for (int jj = 0; jj < P_LEN; jj += 2) {
          stepW1(base + jj, yA);
          if (jj + 2 < P_LEN) {        // reload issued now, consumed next-next step
            const float4* s = (const float4*)hbuf[q][(base + jj + 2) & (RING - 1)];
            yA[0] = s[0]; yA[1] = s[1]; yA[2] = s[2]; yA[3] = s[3]; yA[4] = s[4];
          }
          stepW1(base + jj + 1, yB);
          if (jj + 3 < P_LEN) {
            const float4* s = (const float4*)hbuf[q][(base + jj + 3) & (RING - 1)];
            yB[0] = s[0]; yB[1] = s[1]; yB[2] = s[2]; yB[3] = s[3]; yB[4] = s[4];
          }
        }
      }
      __syncthreads();
    }
  }
}

} // namespace

extern "C" void kernel_launch(void* const* d_in, const int* in_sizes, int n_in,
                              void* d_out, int out_size, void* d_ws, size_t ws_size,
                              hipStream_t stream) {
  const float* x    = (const float*)d_in[0];
  const float* Wih0 = (const float*)d_in[1];
  const float* Whh0 = (const float*)d_in[2];
  const float* bih0 = (const float*)d_in[3];
  const float* bhh0 = (const float*)d_in[4];
  const float* Wih1 = (const float*)d_in[5];
  const float* Whh1 = (const float*)d_in[6];
  const float* bih1 = (const float*)d_in[7];
  const float* bhh1 = (const float*)d_in[8];
  float* out = (float*)d_out;

  hipLaunchKernelGGL(lstm2_pair, dim3(B_SZ / QB), dim3(512), 0, stream,
                     x, Wih0, Whh0, bih0, bhh0, Wih1, Whh1, bih1, bhh1, out);
}

// Round 7
// 709.079 us; speedup vs baseline: 1.4535x; 1.4535x over previous
//
#include <hip/hip_runtime.h>

namespace {

typedef float v2f __attribute__((ext_vector_type(2)));

constexpr int T_SEQ = 2048;
constexpr int B_SZ  = 512;
constexpr int C_IN  = 8;
constexpr int H_SZ  = 20;
constexpr int P_LEN = 16;                 // steps per phase (barrier period)
constexpr int N_PH  = T_SEQ / P_LEN;      // 128 phases
constexpr int RING  = 2 * P_LEN;          // 32-slot h0 handoff ring
constexpr float LOG2E = 1.44269504088896340736f;

__device__ __forceinline__ float rlane(float v, int lane) {
  return __int_as_float(__builtin_amdgcn_readlane(__float_as_int(v), lane));
}

template<int S>
__device__ __forceinline__ float quad_bcast(float v) {
  return __int_as_float(__builtin_amdgcn_update_dpp(
      __float_as_int(v), __float_as_int(v), S * 0x55, 0xF, 0xF, true));
}

// Builtin form: compiler may scalarize — OPTIMAL for the h-dot, where the
// scalar splits let the rlane'd SGPR fold inline into v_fma_f32.
__device__ __forceinline__ v2f fma2(v2f a, v2f b, v2f c) {
  return __builtin_elementwise_fma(a, b, c);
}
// Forced-packed form: one v_pk_fma_f32. Use ONLY where all three operands
// are VGPR-resident (x-dot, y-dot) — halves instruction count there.
__device__ __forceinline__ v2f pk_fma(v2f a, v2f b, v2f c) {
  v2f d;
  asm("v_pk_fma_f32 %0, %1, %2, %3" : "=v"(d) : "v"(a), "v"(b), "v"(c));
  return d;
}
__device__ __forceinline__ v2f splat2(float s) { v2f r; r.x = s; r.y = s; return r; }
__device__ __forceinline__ v2f zero2() { v2f r; r.x = 0.f; r.y = 0.f; return r; }

// Elementwise activation on both gate sets: sigmoid (g!=2) / tanh (g==2).
// cm has log2e pre-folded; tanh(x) = 2*sigmoid(2x)-1.
__device__ __forceinline__ v2f act2(v2f a, float cm, float am, float ad) {
  float ex = __builtin_amdgcn_exp2f(a.x * cm);
  float ey = __builtin_amdgcn_exp2f(a.y * cm);
  float sx = __builtin_amdgcn_rcpf(1.0f + ex);
  float sy = __builtin_amdgcn_rcpf(1.0f + ey);
  v2f r; r.x = __fmaf_rn(sx, am, ad); r.y = __fmaf_rn(sy, am, ad);
  return r;
}

__device__ __forceinline__ float fast_tanh(float a) {
  float e = __builtin_amdgcn_exp2f(a * (-2.0f * LOG2E));
  float s = __builtin_amdgcn_rcpf(1.0f + e);
  return __fmaf_rn(s, 2.0f, -1.0f);
}

// h[k] broadcast from lane-distributed regs (set1 at lanes 4k, k<16;
// set2 value for k=16..19 at lanes 4*(k-16)).
#define H_BCAST(ha, hb, k) (((k) < 16) ? rlane((ha), 4 * (k)) : rlane((hb), 4 * ((k) - 16)))

__global__ __attribute__((amdgpu_flat_work_group_size(128, 128),
                          amdgpu_waves_per_eu(1, 1)))
void lstm2_pk(const float* __restrict__ x,
              const float* __restrict__ Wih0, const float* __restrict__ Whh0,
              const float* __restrict__ bih0, const float* __restrict__ bhh0,
              const float* __restrict__ Wih1, const float* __restrict__ Whh1,
              const float* __restrict__ bih1, const float* __restrict__ bhh1,
              float* __restrict__ out)
{
  // h0 handoff ring: 32 steps (2 phases), 20 floats per slot (80 B, 16-aligned).
  __shared__ __align__(16) float hbuf[RING][H_SZ];
  // x staging: double buffer, 16 steps x 8 ch = 128 floats per phase.
  __shared__ __align__(16) float xbuf[2][P_LEN * C_IN];

  const int tid = threadIdx.x;
  const int wv  = tid >> 6;          // 0 = layer-0 wave, 1 = layer-1 wave
  const int l   = tid & 63;
  const int b   = blockIdx.x;
  const int k1  = l >> 2;            // 0..15
  const int g   = l & 3;             // gate slot: 0=i 1=f 2=g 3=o
  const int k2  = 16 + (k1 & 3);     // 16..19 (replicated)
  const int j1  = g * H_SZ + k1;
  const int j2  = g * H_SZ + k2;

  const bool  isg = (g == 2);
  const float cm  = isg ? (-2.0f * LOG2E) : (-LOG2E);
  const float am  = isg ?  2.0f : 1.0f;
  const float ad  = isg ? -1.0f : 0.0f;

  if (wv == 0) {
    // ================= layer-0 producer wave =================
    v2f wx1[C_IN / 2], wx2[C_IN / 2];  // Wih0 rows j1/j2, k-packed
    v2f wh[H_SZ];                      // {Whh0[j1][k], Whh0[j2][k]} gate-set packed
#pragma unroll
    for (int t = 0; t < C_IN / 2; ++t) {
      wx1[t].x = Wih0[j1 * C_IN + 2 * t]; wx1[t].y = Wih0[j1 * C_IN + 2 * t + 1];
      wx2[t].x = Wih0[j2 * C_IN + 2 * t]; wx2[t].y = Wih0[j2 * C_IN + 2 * t + 1];
    }
#pragma unroll
    for (int k = 0; k < H_SZ; ++k) {
      wh[k].x = Whh0[j1 * H_SZ + k]; wh[k].y = Whh0[j2 * H_SZ + k];
    }
    v2f bias2; bias2.x = bih0[j1] + bhh0[j1]; bias2.y = bih0[j2] + bhh0[j2];

    float ha = 0.f, ca = 0.f, hb = 0.f, cb = 0.f;

    // Per-lane x slice: element e in [0,128) of a phase -> step e>>3, channel e&7.
    // Lane l covers e = l and e = l+64 (the latter is +8 steps).
    const float* xl = x + (size_t)(l >> 3) * (B_SZ * C_IN) + b * C_IN + (l & 7);
    const size_t halfph = (size_t)8 * B_SZ * C_IN;
    const size_t phstr  = (size_t)P_LEN * B_SZ * C_IN;

    // Bootstrap: phase 0 committed now; phase 1 stays in flight a whole phase.
    {
      float v0 = xl[0], v1 = xl[halfph];
      xbuf[0][l] = v0; xbuf[0][64 + l] = v1;
    }
    float n0 = xl[phstr], n1 = xl[phstr + halfph];

    for (int p = 0; p <= N_PH; ++p) {
      if (p < N_PH) {
        const int buf = p & 1;
        float4 xc0 = ((const float4*)&xbuf[buf][0])[0];
        float4 xc1 = ((const float4*)&xbuf[buf][0])[1];
        for (int j = 0; j < P_LEN; ++j) {
          const int n = p * P_LEN + j;
          v2f xp[4];
          xp[0].x = xc0.x; xp[0].y = xc0.y; xp[1].x = xc0.z; xp[1].y = xc0.w;
          xp[2].x = xc1.x; xp[2].y = xc1.y; xp[3].x = xc1.z; xp[3].y = xc1.w;
          if (j + 1 < P_LEN) {           // one-step-ahead x prefetch (LDS bcast)
            xc0 = ((const float4*)&xbuf[buf][(j + 1) * C_IN])[0];
            xc1 = ((const float4*)&xbuf[buf][(j + 1) * C_IN])[1];
          }

          // Recurrent dot, gate-set packed, 2 accs (chain depth 10).
          v2f A0 = bias2, A1 = zero2();
#pragma unroll
          for (int k = 0; k < H_SZ; k += 2) {
            float h0 = H_BCAST(ha, hb, k);
            float h1 = H_BCAST(ha, hb, k + 1);
            A0 = fma2(wh[k],     splat2(h0), A0);
            A1 = fma2(wh[k + 1], splat2(h1), A1);
          }
          // Input dot, k-packed per gate set — forced v_pk_fma_f32.
          v2f X1 = zero2(), X2 = zero2();
#pragma unroll
          for (int t = 0; t < C_IN / 2; ++t) {
            X1 = pk_fma(wx1[t], xp[t], X1);
            X2 = pk_fma(wx2[t], xp[t], X2);
          }
          v2f A = A0 + A1;
          A.x += X1.x + X1.y;
          A.y += X2.x + X2.y;

          v2f act = act2(A, cm, am, ad);
          float iv = quad_bcast<0>(act.x), fv = quad_bcast<1>(act.x);
          float gv = quad_bcast<2>(act.x), ov = quad_bcast<3>(act.x);
          ca = __fmaf_rn(fv, ca, iv * gv);
          ha = ov * fast_tanh(ca);
          iv = quad_bcast<0>(act.y); fv = quad_bcast<1>(act.y);
          gv = quad_bcast<2>(act.y); ov = quad_bcast<3>(act.y);
          cb = __fmaf_rn(fv, cb, iv * gv);
          hb = ov * fast_tanh(cb);

          const int slot = n & (RING - 1);
          if (g == 0) {
            hbuf[slot][k1] = ha;
            if (k1 < 4) hbuf[slot][16 + k1] = hb;
          }
        }
        // Commit next phase's x (in flight ~16 steps); issue load for p+2.
        if (p + 1 < N_PH) { xbuf[(p + 1) & 1][l] = n0; xbuf[(p + 1) & 1][64 + l] = n1; }
        if (p + 2 < N_PH) {
          n0 = xl[(size_t)(p + 2) * phstr];
          n1 = xl[(size_t)(p + 2) * phstr + halfph];
        }
      }
      __syncthreads();   // 129 barriers total, both waves
    }
  } else {
    // ================= layer-1 consumer wave (lags one phase) =================
    v2f wy1[H_SZ / 2], wy2[H_SZ / 2];  // Wih1 rows j1/j2, k-packed
    v2f wq[H_SZ];                      // {Whh1[j1][k], Whh1[j2][k]} gate-set packed
#pragma unroll
    for (int t = 0; t < H_SZ / 2; ++t) {
      wy1[t].x = Wih1[j1 * H_SZ + 2 * t]; wy1[t].y = Wih1[j1 * H_SZ + 2 * t + 1];
      wy2[t].x = Wih1[j2 * H_SZ + 2 * t]; wy2[t].y = Wih1[j2 * H_SZ + 2 * t + 1];
    }
#pragma unroll
    for (int k = 0; k < H_SZ; ++k) {
      wq[k].x = Whh1[j1 * H_SZ + k]; wq[k].y = Whh1[j2 * H_SZ + k];
    }
    v2f bias2; bias2.x = bih1[j1] + bhh1[j1]; bias2.y = bih1[j2] + bhh1[j2];

    float ha = 0.f, ca = 0.f, hb = 0.f, cb = 0.f;
    float* op = out + b * H_SZ;

    auto stepW1 = [&](int n, const float4 (&yq)[5]) {
      v2f yp[H_SZ / 2];
      yp[0].x = yq[0].x; yp[0].y = yq[0].y; yp[1].x = yq[0].z; yp[1].y = yq[0].w;
      yp[2].x = yq[1].x; yp[2].y = yq[1].y; yp[3].x = yq[1].z; yp[3].y = yq[1].w;
      yp[4].x = yq[2].x; yp[4].y = yq[2].y; yp[5].x = yq[2].z; yp[5].y = yq[2].w;
      yp[6].x = yq[3].x; yp[6].y = yq[3].y; yp[7].x = yq[3].z; yp[7].y = yq[3].w;
      yp[8].x = yq[4].x; yp[8].y = yq[4].y; yp[9].x = yq[4].z; yp[9].y = yq[4].w;

      // y-stream: k-packed per gate set, 2 accs each — forced v_pk_fma_f32.
      v2f Y1a = zero2(), Y1b = zero2(), Y2a = zero2(), Y2b = zero2();
#pragma unroll
      for (int t = 0; t < H_SZ / 2; t += 2) {
        Y1a = pk_fma(wy1[t],     yp[t],     Y1a);
        Y2a = pk_fma(wy2[t],     yp[t],     Y2a);
        Y1b = pk_fma(wy1[t + 1], yp[t + 1], Y1b);
        Y2b = pk_fma(wy2[t + 1], yp[t + 1], Y2b);
      }
      // q-stream (h1 recurrence): gate-set packed, 2 accs (chain depth 10).
      v2f Q0 = bias2, Q1 = zero2();
#pragma unroll
      for (int k = 0; k < H_SZ; k += 2) {
        float q0 = H_BCAST(ha, hb, k);
        float q1 = H_BCAST(ha, hb, k + 1);
        Q0 = fma2(wq[k],     splat2(q0), Q0);
        Q1 = fma2(wq[k + 1], splat2(q1), Q1);
      }
      v2f A = Q0 + Q1;
      v2f Y1 = Y1a + Y1b, Y2 = Y2a + Y2b;
      A.x += Y1.x + Y1.y;
      A.y += Y2.x + Y2.y;

      v2f act = act2(A, cm, am, ad);
      float iv = quad_bcast<0>(act.x), fv = quad_bcast<1>(act.x);
      float gv = quad_bcast<2>(act.x), ov = quad_bcast<3>(act.x);
      ca = __fmaf_rn(fv, ca, iv * gv);
      ha = ov * fast_tanh(ca);
      iv = quad_bcast<0>(act.y); fv = quad_bcast<1>(act.y);
      gv = quad_bcast<2>(act.y); ov = quad_bcast<3>(act.y);
      cb = __fmaf_rn(fv, cb, iv * gv);
      hb = ov * fast_tanh(cb);

      if (g == 0) {
        op[k1] = ha;
        if (k1 < 4) op[16 + k1] = hb;
      }
      op += B_SZ * H_SZ;
    };

    for (int p = 0; p <= N_PH; ++p) {
      if (p >= 1) {
        const int base = (p - 1) * P_LEN;
        float4 yA[5], yB[5];
        {
          const float4* s = (const float4*)hbuf[base & (RING - 1)];
          yA[0] = s[0]; yA[1] = s[1]; yA[2] = s[2]; yA[3] = s[3]; yA[4] = s[4];
        }
        {
          const float4* s = (const float4*)hbuf[(base + 1) & (RING - 1)];
          yB[0] = s[0]; yB[1] = s[1]; yB[2] = s[2]; yB[3] = s[3]; yB[4] = s[4];
        }
        for (int jj = 0; jj < P_LEN; jj += 2) {
          stepW1(base + jj, yA);
          if (jj + 2 < P_LEN) {        // reload issued now, consumed next-next step
            const float4* s = (const float4*)hbuf[(base + jj + 2) & (RING - 1)];
            yA[0] = s[0]; yA[1] = s[1]; yA[2] = s[2]; yA[3] = s[3]; yA[4] = s[4];
          }
          stepW1(base + jj + 1, yB);
          if (jj + 3 < P_LEN) {
            const float4* s = (const float4*)hbuf[(base + jj + 3) & (RING - 1)];
            yB[0] = s[0]; yB[1] = s[1]; yB[2] = s[2]; yB[3] = s[3]; yB[4] = s[4];
          }
        }
      }
      __syncthreads();
    }
  }
}

} // namespace

extern "C" void kernel_launch(void* const* d_in, const int* in_sizes, int n_in,
                              void* d_out, int out_size, void* d_ws, size_t ws_size,
                              hipStream_t stream) {
  const float* x    = (const float*)d_in[0];
  const float* Wih0 = (const float*)d_in[1];
  const float* Whh0 = (const float*)d_in[2];
  const float* bih0 = (const float*)d_in[3];
  const float* bhh0 = (const float*)d_in[4];
  const float* Wih1 = (const float*)d_in[5];
  const float* Whh1 = (const float*)d_in[6];
  const float* bih1 = (const float*)d_in[7];
  const float* bhh1 = (const float*)d_in[8];
  float* out = (float*)d_out;

  hipLaunchKernelGGL(lstm2_pk, dim3(B_SZ), dim3(128), 0, stream,
                     x, Wih0, Whh0, bih0, bhh0, Wih1, Whh1, bih1, bhh1, out);
}

// Round 8
// 566.161 us; speedup vs baseline: 1.8204x; 1.2524x over previous
//
#include <hip/hip_runtime.h>

namespace {

typedef float v2f __attribute__((ext_vector_type(2)));

constexpr int T_SEQ = 2048;
constexpr int B_SZ  = 512;
constexpr int C_IN  = 8;
constexpr int H_SZ  = 20;
constexpr int P_LEN = 16;                 // steps per phase (barrier period)
constexpr int N_PH  = T_SEQ / P_LEN;      // 128 phases
constexpr int RING  = 2 * P_LEN;          // 32-slot rings (2 phases)
constexpr float LOG2E = 1.44269504088896340736f;

__device__ __forceinline__ float rlane(float v, int lane) {
  return __int_as_float(__builtin_amdgcn_readlane(__float_as_int(v), lane));
}

template<int S>
__device__ __forceinline__ float quad_bcast(float v) {
  return __int_as_float(__builtin_amdgcn_update_dpp(
      __float_as_int(v), __float_as_int(v), S * 0x55, 0xF, 0xF, true));
}

__device__ __forceinline__ v2f fma2(v2f a, v2f b, v2f c) {
  return __builtin_elementwise_fma(a, b, c);   // -> v_pk_fma_f32 / scalar pair
}
__device__ __forceinline__ v2f splat2(float s) { v2f r; r.x = s; r.y = s; return r; }
__device__ __forceinline__ v2f zero2() { v2f r; r.x = 0.f; r.y = 0.f; return r; }

// Elementwise activation on both gate sets: sigmoid (g!=2) / tanh (g==2).
__device__ __forceinline__ v2f act2(v2f a, float cm, float am, float ad) {
  float ex = __builtin_amdgcn_exp2f(a.x * cm);
  float ey = __builtin_amdgcn_exp2f(a.y * cm);
  float sx = __builtin_amdgcn_rcpf(1.0f + ex);
  float sy = __builtin_amdgcn_rcpf(1.0f + ey);
  v2f r; r.x = __fmaf_rn(sx, am, ad); r.y = __fmaf_rn(sy, am, ad);
  return r;
}

__device__ __forceinline__ float fast_tanh(float a) {
  float e = __builtin_amdgcn_exp2f(a * (-2.0f * LOG2E));
  float s = __builtin_amdgcn_rcpf(1.0f + e);
  return __fmaf_rn(s, 2.0f, -1.0f);
}

// h[k] broadcast from lane-distributed regs (set1 at lanes 4k, k<16;
// set2 value for k=16..19 at lanes 4*(k-16)).
#define H_BCAST(ha, hb, k) (((k) < 16) ? rlane((ha), 4 * (k)) : rlane((hb), 4 * ((k) - 16)))

// 8 waves/block = 2 batches x 4 roles, forced 2 waves/SIMD.
// Wave->SIMD round-robin (i % 4) pairs each chain wave with a light feeder:
//   SIMD0 {w0=L0(b0), w4=fy(b0)}  SIMD1 {w1=L1(b0), w5=fx(b0)}
//   SIMD2 {w2=L0(b1), w6=fy(b1)}  SIMD3 {w3=L1(b1), w7=fx(b1)}
// Feeder issue slots fill the chain waves' dependency-stall cycles.
__global__ __attribute__((amdgpu_flat_work_group_size(512, 512),
                          amdgpu_waves_per_eu(2, 2)))
void lstm2_4role(const float* __restrict__ x,
                 const float* __restrict__ Wih0, const float* __restrict__ Whh0,
                 const float* __restrict__ bih0, const float* __restrict__ bhh0,
                 const float* __restrict__ Wih1, const float* __restrict__ Whh1,
                 const float* __restrict__ bih1, const float* __restrict__ bhh1,
                 float* __restrict__ out)
{
  // Per-batch rings, [bb] = batch-in-block.
  __shared__ __align__(16) float hbuf[2][RING][H_SZ];   // L0 -> fy
  __shared__ __align__(16) v2f   ybuf[2][RING][64];     // fy -> L1 (16 KB each)
  __shared__ __align__(16) v2f   xsbuf[2][RING][64];    // fx -> L0 (16 KB each)
  __shared__ __align__(16) float xbuf[2][P_LEN * C_IN]; // fx-private x stage

  const int tid = threadIdx.x;
  const int wv  = tid >> 6;
  const int l   = tid & 63;
  const int bb  = (wv < 4) ? (wv >> 1) : ((wv - 4) >> 1);
  const int b   = blockIdx.x * 2 + bb;
  const int k1  = l >> 2;            // 0..15
  const int g   = l & 3;             // gate slot: 0=i 1=f 2=g 3=o
  const int k2  = 16 + (k1 & 3);     // 16..19 (replicated)
  const int j1  = g * H_SZ + k1;
  const int j2  = g * H_SZ + k2;

  const bool  isg = (g == 2);
  const float cm  = isg ? (-2.0f * LOG2E) : (-LOG2E);
  const float am  = isg ?  2.0f : 1.0f;
  const float ad  = isg ? -1.0f : 0.0f;

  if (wv < 4 && (wv & 1) == 0) {
    // ================= L0 recurrence chain (batch bb) =================
    v2f wh[H_SZ];
#pragma unroll
    for (int k = 0; k < H_SZ; ++k) {
      wh[k].x = Whh0[j1 * H_SZ + k]; wh[k].y = Whh0[j2 * H_SZ + k];
    }
    v2f bias2; bias2.x = bih0[j1] + bhh0[j1]; bias2.y = bih0[j2] + bhh0[j2];

    float ha = 0.f, ca = 0.f, hb = 0.f, cb = 0.f;

    for (int s = 0; s <= N_PH + 2; ++s) {
      if (s >= 1 && s <= N_PH) {
        const int p0 = s - 1;
        v2f XsCur = xsbuf[bb][(p0 * P_LEN) & (RING - 1)][l];
        for (int j = 0; j < P_LEN; ++j) {
          const int n = p0 * P_LEN + j;
          const int slot = n & (RING - 1);
          v2f Xs = XsCur;
          if (j + 1 < P_LEN)
            XsCur = xsbuf[bb][(n + 1) & (RING - 1)][l];

          v2f A0 = bias2, A1 = Xs;
#pragma unroll
          for (int k = 0; k < H_SZ; k += 2) {
            float h0 = H_BCAST(ha, hb, k);
            float h1 = H_BCAST(ha, hb, k + 1);
            A0 = fma2(wh[k],     splat2(h0), A0);
            A1 = fma2(wh[k + 1], splat2(h1), A1);
          }
          v2f A = A0 + A1;

          v2f act = act2(A, cm, am, ad);
          float iv = quad_bcast<0>(act.x), fv = quad_bcast<1>(act.x);
          float gv = quad_bcast<2>(act.x), ov = quad_bcast<3>(act.x);
          ca = __fmaf_rn(fv, ca, iv * gv);
          ha = ov * fast_tanh(ca);
          iv = quad_bcast<0>(act.y); fv = quad_bcast<1>(act.y);
          gv = quad_bcast<2>(act.y); ov = quad_bcast<3>(act.y);
          cb = __fmaf_rn(fv, cb, iv * gv);
          hb = ov * fast_tanh(cb);

          if (g == 0) {
            hbuf[bb][slot][k1] = ha;
            if (k1 < 4) hbuf[bb][slot][16 + k1] = hb;
          }
        }
      }
      __syncthreads();
    }
  } else if (wv < 4) {
    // ================= L1 recurrence chain (batch bb, lags 3) ==============
    v2f wq[H_SZ];
#pragma unroll
    for (int k = 0; k < H_SZ; ++k) {
      wq[k].x = Whh1[j1 * H_SZ + k]; wq[k].y = Whh1[j2 * H_SZ + k];
    }
    v2f bias2; bias2.x = bih1[j1] + bhh1[j1]; bias2.y = bih1[j2] + bhh1[j2];

    float ha = 0.f, ca = 0.f, hb = 0.f, cb = 0.f;
    float* op = out + b * H_SZ;

    for (int s = 0; s <= N_PH + 2; ++s) {
      if (s >= 3) {
        const int r = s - 3;
        v2f YsCur = ybuf[bb][(r * P_LEN) & (RING - 1)][l];
        for (int j = 0; j < P_LEN; ++j) {
          const int n = r * P_LEN + j;
          v2f Ys = YsCur;
          if (j + 1 < P_LEN)
            YsCur = ybuf[bb][(n + 1) & (RING - 1)][l];

          v2f Q0 = bias2, Q1 = Ys;
#pragma unroll
          for (int k = 0; k < H_SZ; k += 2) {
            float q0 = H_BCAST(ha, hb, k);
            float q1 = H_BCAST(ha, hb, k + 1);
            Q0 = fma2(wq[k],     splat2(q0), Q0);
            Q1 = fma2(wq[k + 1], splat2(q1), Q1);
          }
          v2f A = Q0 + Q1;

          v2f act = act2(A, cm, am, ad);
          float iv = quad_bcast<0>(act.x), fv = quad_bcast<1>(act.x);
          float gv = quad_bcast<2>(act.x), ov = quad_bcast<3>(act.x);
          ca = __fmaf_rn(fv, ca, iv * gv);
          ha = ov * fast_tanh(ca);
          iv = quad_bcast<0>(act.y); fv = quad_bcast<1>(act.y);
          gv = quad_bcast<2>(act.y); ov = quad_bcast<3>(act.y);
          cb = __fmaf_rn(fv, cb, iv * gv);
          hb = ov * fast_tanh(cb);

          if (g == 0) {
            op[k1] = ha;
            if (k1 < 4) op[16 + k1] = hb;
          }
          op += B_SZ * H_SZ;
        }
      }
      __syncthreads();
    }
  } else if ((wv & 1) == 0) {
    // ================= feeder-y (batch bb): Ys[s-2] = Wih1 . y0 ============
    v2f wy1[H_SZ / 2], wy2[H_SZ / 2];
#pragma unroll
    for (int t = 0; t < H_SZ / 2; ++t) {
      wy1[t].x = Wih1[j1 * H_SZ + 2 * t]; wy1[t].y = Wih1[j1 * H_SZ + 2 * t + 1];
      wy2[t].x = Wih1[j2 * H_SZ + 2 * t]; wy2[t].y = Wih1[j2 * H_SZ + 2 * t + 1];
    }

    for (int s = 0; s <= N_PH + 2; ++s) {
      if (s >= 2 && s <= N_PH + 1) {
        const int q = s - 2;
        for (int j = 0; j < P_LEN; ++j) {
          const int slot = (q * P_LEN + j) & (RING - 1);
          const float4* sp = (const float4*)hbuf[bb][slot];
          float4 y0 = sp[0], y1 = sp[1], y2 = sp[2], y3 = sp[3], y4 = sp[4];
          v2f yp[H_SZ / 2];
          yp[0].x = y0.x; yp[0].y = y0.y; yp[1].x = y0.z; yp[1].y = y0.w;
          yp[2].x = y1.x; yp[2].y = y1.y; yp[3].x = y1.z; yp[3].y = y1.w;
          yp[4].x = y2.x; yp[4].y = y2.y; yp[5].x = y2.z; yp[5].y = y2.w;
          yp[6].x = y3.x; yp[6].y = y3.y; yp[7].x = y3.z; yp[7].y = y3.w;
          yp[8].x = y4.x; yp[8].y = y4.y; yp[9].x = y4.z; yp[9].y = y4.w;

          v2f Y1a = zero2(), Y1b = zero2(), Y2a = zero2(), Y2b = zero2();
#pragma unroll
          for (int t = 0; t < H_SZ / 2; t += 2) {
            Y1a = fma2(wy1[t],     yp[t],     Y1a);
            Y2a = fma2(wy2[t],     yp[t],     Y2a);
            Y1b = fma2(wy1[t + 1], yp[t + 1], Y1b);
            Y2b = fma2(wy2[t + 1], yp[t + 1], Y2b);
          }
          v2f Y1 = Y1a + Y1b, Y2 = Y2a + Y2b;
          v2f Ys; Ys.x = Y1.x + Y1.y; Ys.y = Y2.x + Y2.y;
          ybuf[bb][slot][l] = Ys;
        }
      }
      __syncthreads();
    }
  } else {
    // ================= feeder-x (batch bb): Xs[s] = Wih0 . x ===============
    v2f wx1[C_IN / 2], wx2[C_IN / 2];
#pragma unroll
    for (int t = 0; t < C_IN / 2; ++t) {
      wx1[t].x = Wih0[j1 * C_IN + 2 * t]; wx1[t].y = Wih0[j1 * C_IN + 2 * t + 1];
      wx2[t].x = Wih0[j2 * C_IN + 2 * t]; wx2[t].y = Wih0[j2 * C_IN + 2 * t + 1];
    }

    const float* xl = x + (size_t)(l >> 3) * (B_SZ * C_IN) + b * C_IN + (l & 7);
    const size_t halfph = (size_t)8 * B_SZ * C_IN;
    const size_t phstr  = (size_t)P_LEN * B_SZ * C_IN;

    float cur0 = xl[0],     cur1 = xl[halfph];            // phase 0
    float nx0  = xl[phstr], nx1  = xl[phstr + halfph];    // phase 1

    for (int s = 0; s <= N_PH + 2; ++s) {
      if (s <= N_PH - 1) {
        xbuf[bb][l] = cur0; xbuf[bb][64 + l] = cur1;
        asm volatile("s_waitcnt lgkmcnt(0)" ::: "memory");
        float4 xc0 = ((const float4*)&xbuf[bb][0])[0];
        float4 xc1 = ((const float4*)&xbuf[bb][0])[1];
        for (int j = 0; j < P_LEN; ++j) {
          v2f xp[4];
          xp[0].x = xc0.x; xp[0].y = xc0.y; xp[1].x = xc0.z; xp[1].y = xc0.w;
          xp[2].x = xc1.x; xp[2].y = xc1.y; xp[3].x = xc1.z; xp[3].y = xc1.w;
          if (j + 1 < P_LEN) {
            xc0 = ((const float4*)&xbuf[bb][(j + 1) * C_IN])[0];
            xc1 = ((const float4*)&xbuf[bb][(j + 1) * C_IN])[1];
          }
          v2f X1 = zero2(), X2 = zero2();
#pragma unroll
          for (int t = 0; t < C_IN / 2; ++t) {
            X1 = fma2(wx1[t], xp[t], X1);
            X2 = fma2(wx2[t], xp[t], X2);
          }
          v2f Xs; Xs.x = X1.x + X1.y; Xs.y = X2.x + X2.y;
          xsbuf[bb][(s * P_LEN + j) & (RING - 1)][l] = Xs;
        }
        cur0 = nx0; cur1 = nx1;
        if (s + 2 <= N_PH - 1) {
          nx0 = xl[(size_t)(s + 2) * phstr];
          nx1 = xl[(size_t)(s + 2) * phstr + halfph];
        }
      }
      __syncthreads();
    }
  }
}

} // namespace

extern "C" void kernel_launch(void* const* d_in, const int* in_sizes, int n_in,
                              void* d_out, int out_size, void* d_ws, size_t ws_size,
                              hipStream_t stream) {
  const float* x    = (const float*)d_in[0];
  const float* Wih0 = (const float*)d_in[1];
  const float* Whh0 = (const float*)d_in[2];
  const float* bih0 = (const float*)d_in[3];
  const float* bhh0 = (const float*)d_in[4];
  const float* Wih1 = (const float*)d_in[5];
  const float* Whh1 = (const float*)d_in[6];
  const float* bih1 = (const float*)d_in[7];
  const float* bhh1 = (const float*)d_in[8];
  float* out = (float*)d_out;

  hipLaunchKernelGGL(lstm2_4role, dim3(B_SZ / 2), dim3(512), 0, stream,
                     x, Wih0, Whh0, bih0, bhh0, Wih1, Whh1, bih1, bhh1, out);
}